// Round 1
// baseline (100.344 us; speedup 1.0000x reference)
//
#include <hip/hip_runtime.h>
#include <hip/hip_bf16.h>

#define BD 2
#define TT 1024
#define HH 8
#define DD 64
#define NLEV 11
#define RT 64
#define NT (TT / RT)      // 16 row tiles per (b,h)
#define LSTR 72           // LDS row stride in bf16 elems: 144B, 16B-aligned, 2-way bank alias (free)

typedef __bf16 bf16;
typedef bf16 bf16x2 __attribute__((ext_vector_type(2)));
typedef bf16 bf16x4 __attribute__((ext_vector_type(4)));
typedef bf16 bf16x8 __attribute__((ext_vector_type(8)));
typedef float floatx4 __attribute__((ext_vector_type(4)));

// Kernel 1: cs[bh][t] = inclusive cumsum over t of g[b,t,h]
__global__ __launch_bounds__(256) void cumsum_kernel(const float* __restrict__ g,
                                                     float* __restrict__ cs) {
    const int bh = blockIdx.x;           // 0..15
    const int b = bh >> 3, h = bh & 7;
    const int t = threadIdx.x;           // 0..255, each owns 4 elems
    __shared__ float part[256];

    float v0[4];
    float s = 0.f;
#pragma unroll
    for (int u = 0; u < 4; ++u) {
        s += g[(b * TT + (t * 4 + u)) * HH + h];
        v0[u] = s;
    }
    part[t] = s;
    __syncthreads();
    float x = s;
    for (int off = 1; off < 256; off <<= 1) {
        float y = (t >= off) ? part[t - off] : 0.f;
        __syncthreads();
        x += y;
        part[t] = x;
        __syncthreads();
    }
    const float excl = x - s;
#pragma unroll
    for (int u = 0; u < 4; ++u) cs[bh * TT + t * 4 + u] = excl + v0[u];
}

// Kernel 2: main hierarchical-attention kernel.
// grid = 16 bh * 16 row-tiles; block = 512 threads = 8 waves:
//   wave = (ch<<2)|mwave : mwave picks 16-row strip, ch picks 32-col half.
__global__ __launch_bounds__(512) void hattn_kernel(
    const float* __restrict__ q, const float* __restrict__ k,
    const float* __restrict__ v, const float* __restrict__ L,
    const float* __restrict__ cs, float* __restrict__ out) {
    const int blk = blockIdx.x;
    const int bh = blk >> 4;          // 0..15
    const int rt = blk & 15;          // row tile
    const int b = bh >> 3, h = bh & 7;
    const int tid = threadIdx.x;
    const int lane = tid & 63;
    const int wave = tid >> 6;        // 0..7
    const int mwave = wave & 3;       // row strip
    const int ch = wave >> 2;         // col half
    const int m0 = mwave * 16;
    const int lrow = lane & 15;
    const int lk = lane >> 4;

    __shared__ bf16 Qs[RT * LSTR];
    __shared__ bf16 Ks[RT * LSTR];
    __shared__ bf16 Vt[DD * LSTR];    // transposed: Vt[p][j]
    __shared__ bf16 Ps[RT * LSTR];
    __shared__ float Ls[NLEV * RT];   // Ls[lev][row_local]
    __shared__ float csRow[RT];
    __shared__ float csCol[RT];

    // ---- one-time loads: Q tile (as bf16), level scales for our rows, cs rows ----
    {
        const int il = tid >> 3, d0 = (tid & 7) * 8;
        const float* qp = q + ((size_t)((b * TT + rt * RT + il) * HH) + h) * DD + d0;
#pragma unroll
        for (int u = 0; u < 8; u += 4) {
            float4 f = *(const float4*)(qp + u);
            bf16x4 w4 = {(bf16)f.x, (bf16)f.y, (bf16)f.z, (bf16)f.w};
            *(bf16x4*)&Qs[il * LSTR + d0 + u] = w4;
        }
    }
    for (int u = tid; u < NLEV * RT; u += 512)
        Ls[u] = L[((size_t)bh * NLEV + (u >> 6)) * TT + rt * RT + (u & 63)];
    if (tid < RT) csRow[tid] = cs[bh * TT + rt * RT + tid];

    floatx4 O0 = {0.f, 0.f, 0.f, 0.f};
    floatx4 O1 = {0.f, 0.f, 0.f, 0.f};

    for (int ct = 0; ct <= rt; ++ct) {
        __syncthreads();  // protect prev-iter LDS reads before overwrite
        // ---- stage K tile (bf16) ----
        {
            const int jl = tid >> 3, d0 = (tid & 7) * 8;
            const float* kp = k + ((size_t)((b * TT + ct * RT + jl) * HH) + h) * DD + d0;
#pragma unroll
            for (int u = 0; u < 8; u += 4) {
                float4 f = *(const float4*)(kp + u);
                bf16x4 w4 = {(bf16)f.x, (bf16)f.y, (bf16)f.z, (bf16)f.w};
                *(bf16x4*)&Ks[jl * LSTR + d0 + u] = w4;
            }
        }
        // ---- stage V transposed (bf16): Vt[p][j] ----
        {
            const int jp = tid >> 4;       // 0..31 -> j pair
            const int p0 = tid & 15;
            const float* vp0 = v + ((size_t)((b * TT + ct * RT + 2 * jp) * HH) + h) * DD;
            const float* vp1 = vp0 + HH * DD;
#pragma unroll
            for (int it = 0; it < 4; ++it) {
                const int p = p0 + it * 16;
                bf16x2 w2 = {(bf16)vp0[p], (bf16)vp1[p]};
                *(bf16x2*)&Vt[p * LSTR + jp * 2] = w2;
            }
        }
        if (tid < RT) csCol[tid] = cs[bh * TT + ct * RT + tid];
        __syncthreads();

        // ---- S = Q K^T (bf16 MFMA, fp32 acc), then apply decay*level weight ----
        bf16x8 a0 = *(bf16x8*)&Qs[(m0 + lrow) * LSTR + lk * 8];
        bf16x8 a1 = *(bf16x8*)&Qs[(m0 + lrow) * LSTR + 32 + lk * 8];
        float csr[4];
#pragma unroll
        for (int r = 0; r < 4; ++r) csr[r] = csRow[m0 + lk * 4 + r];
#pragma unroll
        for (int nbi = 0; nbi < 2; ++nbi) {
            const int c0 = (ch * 2 + nbi) * 16;
            bf16x8 b0 = *(bf16x8*)&Ks[(c0 + lrow) * LSTR + lk * 8];
            bf16x8 b1 = *(bf16x8*)&Ks[(c0 + lrow) * LSTR + 32 + lk * 8];
            floatx4 sacc = {0.f, 0.f, 0.f, 0.f};
            sacc = __builtin_amdgcn_mfma_f32_16x16x32_bf16(a0, b0, sacc, 0, 0, 0);
            sacc = __builtin_amdgcn_mfma_f32_16x16x32_bf16(a1, b1, sacc, 0, 0, 0);
            const int jg = ct * RT + c0 + lrow;       // global col (key idx)
            const float csj = csCol[c0 + lrow];
#pragma unroll
            for (int r = 0; r < 4; ++r) {
                const int rowl = m0 + lk * 4 + r;
                const int ig = rt * RT + rowl;        // global row (query idx)
                float wgt = 0.f;
                if (jg <= ig) {
                    const int x = ig ^ jg;
                    const int lev = x ? (32 - __clz(x)) : 0;
                    wgt = __expf(csr[r] - csj) * Ls[lev * RT + rowl];
                }
                Ps[rowl * LSTR + c0 + lrow] = (bf16)(sacc[r] * wgt);
            }
        }
        __syncthreads();  // P halves written by both col-half waves

        // ---- O += P V (A = P rows strip, B = Vt) ----
        bf16x8 pa0 = *(bf16x8*)&Ps[(m0 + lrow) * LSTR + lk * 8];
        bf16x8 pa1 = *(bf16x8*)&Ps[(m0 + lrow) * LSTR + 32 + lk * 8];
        {
            const int c0 = (ch * 2 + 0) * 16;
            bf16x8 vb0 = *(bf16x8*)&Vt[(c0 + lrow) * LSTR + lk * 8];
            bf16x8 vb1 = *(bf16x8*)&Vt[(c0 + lrow) * LSTR + 32 + lk * 8];
            O0 = __builtin_amdgcn_mfma_f32_16x16x32_bf16(pa0, vb0, O0, 0, 0, 0);
            O0 = __builtin_amdgcn_mfma_f32_16x16x32_bf16(pa1, vb1, O0, 0, 0, 0);
        }
        {
            const int c0 = (ch * 2 + 1) * 16;
            bf16x8 vb0 = *(bf16x8*)&Vt[(c0 + lrow) * LSTR + lk * 8];
            bf16x8 vb1 = *(bf16x8*)&Vt[(c0 + lrow) * LSTR + 32 + lk * 8];
            O1 = __builtin_amdgcn_mfma_f32_16x16x32_bf16(pa0, vb0, O1, 0, 0, 0);
            O1 = __builtin_amdgcn_mfma_f32_16x16x32_bf16(pa1, vb1, O1, 0, 0, 0);
        }
    }

    // ---- epilogue: store O (fp32) ----
#pragma unroll
    for (int r = 0; r < 4; ++r) {
        const int rowl = m0 + lk * 4 + r;
        const int ig = rt * RT + rowl;
        float* op = out + ((size_t)((b * TT + ig) * HH) + h) * DD;
        op[(ch * 2 + 0) * 16 + lrow] = O0[r];
        op[(ch * 2 + 1) * 16 + lrow] = O1[r];
    }
}

extern "C" void kernel_launch(void* const* d_in, const int* in_sizes, int n_in,
                              void* d_out, int out_size, void* d_ws, size_t ws_size,
                              hipStream_t stream) {
    const float* q = (const float*)d_in[0];
    const float* k = (const float*)d_in[1];
    const float* v = (const float*)d_in[2];
    const float* g = (const float*)d_in[3];
    const float* L = (const float*)d_in[4];
    float* out = (float*)d_out;
    float* cs = (float*)d_ws;  // 16*1024 floats

    cumsum_kernel<<<BD * HH, 256, 0, stream>>>(g, cs);
    hattn_kernel<<<BD * HH * NT, 512, 0, stream>>>(q, k, v, L, cs, out);
}